// Round 11
// baseline (1691.661 us; speedup 1.0000x reference)
//
#include <hip/hip_runtime.h>
#include <hip/hip_bf16.h>

#define BB 2
#define TT 2048
#define DD 1024
#define HH 8
#define HKk 512
#define BTt 4096  // BB*TT
#define PREPSZ 2304  // floats per (bh,tile) prep block

typedef unsigned short u16;
typedef __attribute__((ext_vector_type(8))) short bf16x8;
typedef __attribute__((ext_vector_type(4))) float f32x4;

__device__ __forceinline__ u16 f2bf(float v) {
  union { float f; unsigned u; } c; c.f = v;
  return (u16)((c.u + 0x7fffu + ((c.u >> 16) & 1u)) >> 16);  // RNE
}
__device__ __forceinline__ float bf2f(u16 v) {
  union { unsigned u; float f; } c; c.u = ((unsigned)v) << 16; return c.f;
}
__device__ __forceinline__ float sigm(float x) { return 1.f / (1.f + expf(-x)); }

// ---------- weight transpose + cast: dst_bf16[n*K+k] = src_f32[k*N+n] ----------
__global__ __launch_bounds__(256) void ktrans(const float* __restrict__ src,
                                              u16* __restrict__ dst, int K, int N) {
  __shared__ u16 t[32][33];
  int n0 = blockIdx.x * 32, k0 = blockIdx.y * 32;
  int tx = threadIdx.x & 31, ty0 = threadIdx.x >> 5;
#pragma unroll
  for (int i = 0; i < 32; i += 8)
    t[ty0 + i][tx] = f2bf(src[(size_t)(k0 + ty0 + i) * N + n0 + tx]);
  __syncthreads();
#pragma unroll
  for (int i = 0; i < 32; i += 8)
    dst[(size_t)(n0 + ty0 + i) * K + k0 + tx] = t[tx][ty0 + i];
}

// ---------- RMS norm over 1024 cols ----------
__global__ __launch_bounds__(256) void krms(const float* __restrict__ x,
                                            const float* __restrict__ w,
                                            void* __restrict__ out, int obf) {
  size_t row = blockIdx.x;
  __shared__ float red[4];
  float vals[4];
  float s = 0.f;
#pragma unroll
  for (int i = 0; i < 4; i++) {
    vals[i] = x[row * DD + threadIdx.x + i * 256];
    s += vals[i] * vals[i];
  }
#pragma unroll
  for (int off = 32; off; off >>= 1) s += __shfl_xor(s, off);
  if ((threadIdx.x & 63) == 0) red[threadIdx.x >> 6] = s;
  __syncthreads();
  float tot = red[0] + red[1] + red[2] + red[3];
  float sc = rsqrtf(tot * (1.f / DD) + 1e-6f);
#pragma unroll
  for (int i = 0; i < 4; i++) {
    size_t idx = row * DD + threadIdx.x + i * 256;
    float vv = vals[i] * sc * w[threadIdx.x + i * 256];
    if (obf) ((u16*)out)[idx] = f2bf(vv);
    else ((float*)out)[idx] = vv;
  }
}

// ---------- causal depthwise conv (KW=4) + bias + SiLU: f32 -> bf16 ----------
__global__ __launch_bounds__(256) void kconv(const float* __restrict__ hin,
                                             const float* __restrict__ cw,
                                             const float* __restrict__ cb,
                                             u16* __restrict__ hout) {
  size_t i = (size_t)blockIdx.x * 256 + threadIdx.x;
  int d = (int)(i & 1023);
  int bt = (int)(i >> 10);
  int b = bt >> 11, t = bt & 2047;
  float acc = cb[d];
#pragma unroll
  for (int j = 0; j < 4; j++) {
    int tt = t - 3 + j;
    if (tt >= 0) acc += hin[(((size_t)(b * TT + tt)) << 10) + d] * cw[d * 4 + j];
  }
  hout[i] = f2bf(acc * sigm(acc));
}

// ---------- small f32-compute GEMM ----------
__global__ __launch_bounds__(256) void kgemm(const void* __restrict__ A, int abf,
                                             const float* __restrict__ Bm,
                                             const float* __restrict__ bias,
                                             float* __restrict__ C,
                                             int M, int N, int K, int act) {
  __shared__ __align__(16) float As[16][64];
  __shared__ __align__(16) float Bs[16][64];
  int tid = threadIdx.x;
  int tx = tid & 15, ty = tid >> 4;
  int row0 = blockIdx.y * 64, col0 = blockIdx.x * 64;
  float acc[4][4] = {};
  for (int k0 = 0; k0 < K; k0 += 16) {
#pragma unroll
    for (int l = 0; l < 4; l++) {
      int e = tid * 4 + l;
      int m = e >> 4, kk = e & 15;
      int gr = row0 + m;
      size_t ai = (size_t)gr * K + k0 + kk;
      As[kk][m] = (gr < M) ? (abf ? bf2f(((const u16*)A)[ai]) : ((const float*)A)[ai]) : 0.f;
    }
#pragma unroll
    for (int l = 0; l < 4; l++) {
      int e = tid + l * 256;
      int kk = e >> 6, n = e & 63;
      int gc = col0 + n;
      Bs[kk][n] = (gc < N) ? Bm[(size_t)(k0 + kk) * N + gc] : 0.f;
    }
    __syncthreads();
#pragma unroll
    for (int kk = 0; kk < 16; kk++) {
      float4 av = *(const float4*)&As[kk][ty * 4];
      float4 bv = *(const float4*)&Bs[kk][tx * 4];
      float a[4] = {av.x, av.y, av.z, av.w};
      float b[4] = {bv.x, bv.y, bv.z, bv.w};
#pragma unroll
      for (int i = 0; i < 4; i++)
#pragma unroll
        for (int j = 0; j < 4; j++) acc[i][j] += a[i] * b[j];
    }
    __syncthreads();
  }
#pragma unroll
  for (int i = 0; i < 4; i++) {
    int r = row0 + ty * 4 + i;
    if (r >= M) continue;
#pragma unroll
    for (int j = 0; j < 4; j++) {
      int cc = col0 + tx * 4 + j;
      if (cc >= N) continue;
      float vv = acc[i][j];
      if (bias) vv += bias[cc];
      if (act == 1) vv = vv * sigm(vv);
      else if (act == 2) vv = sigm(vv);
      C[(size_t)r * N + cc] = vv;
    }
  }
}

// ---------- big MFMA GEMM ----------
template <int EPI>
__global__ __launch_bounds__(256) void kmfma(
    const u16* __restrict__ A, int lda, const u16* __restrict__ Bt,
    void* __restrict__ C, int ldc, int M, int N, int K,
    const float* __restrict__ g1f, const float* __restrict__ g2f,
    const float* __restrict__ f1, int silucut) {
  __shared__ __align__(16) u16 As[128 * 72];
  __shared__ __align__(16) u16 Bs[128 * 72];
  int tid = threadIdx.x;
  int lane = tid & 63, wv = tid >> 6;
  int m0 = (wv & 1) * 64, n0 = (wv >> 1) * 64;
  int ml = lane & 15, kq = (lane >> 4) << 3;
  int row0 = blockIdx.y * 128, col0 = blockIdx.x * 128;
  int sr = tid >> 3, sc = (tid & 7) * 8;

  f32x4 acc[4][4];
#pragma unroll
  for (int i = 0; i < 4; i++)
#pragma unroll
    for (int j = 0; j < 4; j++) acc[i][j] = (f32x4){0.f, 0.f, 0.f, 0.f};

  for (int k0 = 0; k0 < K; k0 += 64) {
    __syncthreads();
#pragma unroll
    for (int ri = 0; ri < 4; ri++) {
      bf16x8 a_ld = *(const bf16x8*)&A[(size_t)(row0 + sr + ri * 32) * lda + k0 + sc];
      bf16x8 b_ld = *(const bf16x8*)&Bt[(size_t)(col0 + sr + ri * 32) * K + k0 + sc];
      *(bf16x8*)&As[(sr + ri * 32) * 72 + sc] = a_ld;
      *(bf16x8*)&Bs[(sr + ri * 32) * 72 + sc] = b_ld;
    }
    __syncthreads();
#pragma unroll
    for (int kk = 0; kk < 64; kk += 32) {
      bf16x8 af[4], bfr[4];
#pragma unroll
      for (int i = 0; i < 4; i++)
        af[i] = *(const bf16x8*)&As[(m0 + i * 16 + ml) * 72 + kk + kq];
#pragma unroll
      for (int j = 0; j < 4; j++)
        bfr[j] = *(const bf16x8*)&Bs[(n0 + j * 16 + ml) * 72 + kk + kq];
#pragma unroll
      for (int i = 0; i < 4; i++)
#pragma unroll
        for (int j = 0; j < 4; j++)
          acc[i][j] = __builtin_amdgcn_mfma_f32_16x16x32_bf16(af[i], bfr[j], acc[i][j], 0, 0, 0);
    }
  }
  int rbase = row0 + m0 + ((lane >> 4) << 2);
#pragma unroll
  for (int i = 0; i < 4; i++) {
#pragma unroll
    for (int j = 0; j < 4; j++) {
      int gc = col0 + n0 + j * 16 + ml;
#pragma unroll
      for (int r = 0; r < 4; r++) {
        int gr = rbase + i * 16 + r;
        float v = acc[i][j][r];
        size_t idx = (size_t)gr * ldc + gc;
        if (EPI == 0) {
          ((float*)C)[idx] = v;
        } else if (EPI == 1) {
          if (gc < silucut) v = v * sigm(v);
          ((u16*)C)[idx] = f2bf(v);
        } else if (EPI == 2) {
          ((float*)C)[idx] = g1f[idx] + v * g2f[idx];
        } else {
          ((float*)C)[idx] = f1[idx] + v;
        }
      }
    }
  }
}

// ---------- L2 normalize 64-wide slices of X1 (q|k halves) ----------
__global__ __launch_bounds__(256) void kl2norm(float* __restrict__ X1) {
  int lane = threadIdx.x & 63;
  size_t r64 = (size_t)blockIdx.x * 4 + (threadIdx.x >> 6);
  size_t t = r64 >> 4;
  int sl = (int)(r64 & 15);
  size_t idx = t * 2048 + sl * 64 + lane;
  float vv = X1[idx];
  float s = vv * vv;
#pragma unroll
  for (int off = 32; off; off >>= 1) s += __shfl_xor(s, off);
  X1[idx] = vv / (sqrtf(s) + 1e-6f);
}

// ---------- headwise RMS norm: yat f32 -> bf16 ----------
__global__ __launch_bounds__(256) void kheadnorm(const float* __restrict__ y,
                                                 const float* __restrict__ hw,
                                                 u16* __restrict__ yo) {
  int lane = threadIdx.x & 63;
  size_t r = (size_t)blockIdx.x * 4 + (threadIdx.x >> 6);
  int h = (int)(r & 7);
  float vv = y[r * 64 + lane];
  float s = vv * vv;
#pragma unroll
  for (int off = 32; off; off >>= 1) s += __shfl_xor(s, off);
  yo[r * 64 + lane] = f2bf(vv * rsqrtf(s * (1.f / 64.f) + 1e-6f) * hw[h * 64 + lane]);
}

// ---------- klifA: membrane recurrence only -> packed spike bitmasks ----------
__global__ __launch_bounds__(64) void klifA(const float* __restrict__ dr, int drs,
                                            unsigned* __restrict__ masks) {
  int bh = blockIdx.x;
  int b = bh >> 3, h = bh & 7;
  int lane = threadIdx.x;
  float cur[32], nxt[32];
#pragma unroll
  for (int i = 0; i < 32; i++)
    cur[i] = dr[(size_t)(b * TT + i) * drs + h * 64 + lane];
  float mem = 0.f;
  for (int t0 = 0; t0 < TT; t0 += 32) {
    if (t0 + 32 < TT) {
#pragma unroll
      for (int i = 0; i < 32; i++)
        nxt[i] = dr[(size_t)(b * TT + t0 + 32 + i) * drs + h * 64 + lane];
    }
    unsigned m = 0;
#pragma unroll
    for (int i = 0; i < 32; i++) {
      mem = 0.9f * mem + cur[i];
      int s = (mem > 0.5f) ? 1 : 0;
      mem -= s ? 0.5f : 0.f;
      m |= ((unsigned)s) << i;
    }
    masks[((size_t)bh * 64 + (t0 >> 5)) * 64 + lane] = m;
#pragma unroll
    for (int i = 0; i < 32; i++) cur[i] = nxt[i];
  }
}

// ---------- klifB: gates from spike masks, fully parallel ----------
__global__ __launch_bounds__(64) void klifB(const unsigned* __restrict__ masks,
                                            const float* __restrict__ ab,
                                            const float* __restrict__ bb,
                                            const float* __restrict__ asp,
                                            const float* __restrict__ bsp,
                                            float* __restrict__ alpha,
                                            float* __restrict__ beta) {
  int blk = blockIdx.x;
  int bh = blk >> 4, tc = blk & 15;
  int b = bh >> 3, h = bh & 7;
  int lane = threadIdx.x;
  float aspk = asp[h * 64 + lane];
  float bspk = bsp[h * 64 + lane];
#pragma unroll
  for (int g = 0; g < 2; g++) {
    size_t row0 = (size_t)(b * TT) + tc * 128 + g * 64;
    unsigned m0 = masks[((size_t)bh * 64 + (tc * 4 + g * 2 + 0)) * 64 + lane];
    unsigned m1 = masks[((size_t)bh * 64 + (tc * 4 + g * 2 + 1)) * 64 + lane];
    float bbv = bb[(row0 + lane) * HH + h];
#pragma unroll
    for (int tt = 0; tt < 64; tt++) {
      unsigned mw = (tt < 32) ? m0 : m1;
      int s = (mw >> (tt & 31)) & 1;
      unsigned long long act = __ballot(s != 0);
      float sp = (float)s;
      float r2 = sp * bspk;
#pragma unroll
      for (int off = 32; off; off >>= 1) r2 += __shfl_xor(r2, off);
      float bbi = __shfl(bbv, tt);  // all lanes EXEC-active (r8 lesson)
      size_t rt = row0 + tt;
      float abv = ab[rt * HKk + h * 64 + lane];
      int active = (act != 0ull);
      alpha[rt * HKk + h * 64 + lane] = active ? sigm(abv + aspk * sp) : 1.f;
      if (lane == 0) beta[rt * HH + h] = active ? sigm(bbi + r2) : 0.f;
    }
  }
}

// ---------- kprep: chunk (C=8) UT-transform precompute (r9 proven) ----------
__global__ __launch_bounds__(64) void kprep(const float* __restrict__ X1,
                                            const float* __restrict__ alph,
                                            const float* __restrict__ beta,
                                            float* __restrict__ prep) {
  int blk = blockIdx.x;
  int bh = blk >> 8, T = blk & 255;
  int b = bh >> 3, h = bh & 7;
  int lane = threadIdx.x;
  size_t row0 = (size_t)(b * TT) + (size_t)T * 8;
  float* out = prep + (size_t)blk * PREPSZ;
  __shared__ float sKP[8][64], sKiP[8][64], sQP[8][64];
  __shared__ float sBC[64], sG[64], sW[64], sBeta[8];

  float Pt[8], kv[8], kh[8];
  {
    float P = 1.f;
#pragma unroll
    for (int t = 0; t < 8; t++) {
      size_t rt = row0 + t;
      float a = alph[rt * HKk + h * 64 + lane];
      kv[t] = X1[rt * 2048 + h * 64 + 512 + lane];
      float qv = X1[rt * 2048 + h * 64 + lane];
      P *= a;
      Pt[t] = P;
      sQP[t][lane] = qv * P;
    }
    float P7 = Pt[7];
#pragma unroll
    for (int t = 0; t < 8; t++) {
      float KPv = kv[t] * Pt[t];
      float KiPv = kv[t] / Pt[t];
      sKP[t][lane] = KPv;
      sKiP[t][lane] = KiPv;
      kh[t] = P7 * KiPv;
      out[512 + t * 64 + lane] = sQP[t][lane];  // Q1
    }
    out[2048 + lane] = P7;  // A7
  }
  if (lane < 8) sBeta[lane] = beta[(row0 + lane) * HH + h];
  __syncthreads();
#pragma unroll
  for (int t = 0; t < 8; t++) out[t * 64 + lane] = sBeta[t] * kv[t] * Pt[t];

  int t2 = lane >> 3, s2 = lane & 7;
  {
    float ac = 0.f, ag = 0.f;
#pragma unroll
    for (int k = 0; k < 64; k++) {
      float kip = sKiP[s2][k];
      ac += sKP[t2][k] * kip;
      ag += sQP[t2][k] * kip;
    }
    sBC[lane] = (t2 > s2) ? sBeta[t2] * ac : 0.f;
    sG[lane] = (t2 >= s2) ? ag : 0.f;
  }
  if (lane < 8) sW[lane * 8 + lane] = 1.f;
  __syncthreads();

  for (int t = 1; t < 8; t++) {
    if (lane < t) {
      float a = -sBC[t * 8 + lane];
      for (int s = lane + 1; s < t; s++) a -= sBC[t * 8 + s] * sW[s * 8 + lane];
      sW[t * 8 + lane] = a;
    }
    __syncthreads();
  }
  {
    float gw = 0.f;
    if (s2 <= t2)
      for (int s = s2; s <= t2; s++) gw += sG[t2 * 8 + s] * sW[s * 8 + s2];
    out[2112 + lane] = gw;
  }
#pragma unroll
  for (int r = 0; r < 8; r++) {
    float acc = 0.f;
    for (int s = r; s < 8; s++) acc += kh[s] * sW[s * 8 + r];
    out[1024 + r * 64 + lane] = acc;
  }
#pragma unroll
  for (int t = 0; t < 8; t++)
    out[1536 + t * 64 + lane] = sBeta[t] * X1[(row0 + t) * 2048 + h * 64 + 1024 + lane];
}

// ---------- kscan2: sequential chunk walker, ONE block per bh (512 thr, 8 waves) ----------
// r10 counters: 8 vg-blocks per bh re-streamed the same prep (FETCH 144 MiB @300GB/s
// = the whole 533 us). Now the tile is staged to LDS once and shared by all 8
// vg-waves -> 8x less HBM. wave id = vg; per-wave compute identical to r9.
__global__ __launch_bounds__(512) void kscan2(const float* __restrict__ prep,
                                              float* __restrict__ y) {
  int bh = blockIdx.x;
  int b = bh >> 3, h = bh & 7;
  int tid = threadIdx.x;
  int vg = tid >> 6, lane = tid & 63;
  int kp = lane & 7, vv = lane >> 3;
  const float* gsrc = prep + (size_t)bh * 256 * PREPSZ;
  __shared__ __align__(16) float buf[2][PREPSZ];
  float S[8];
#pragma unroll
  for (int j = 0; j < 8; j++) S[j] = 0.f;

  // stage tile 0 -> LDS, prefetch tile 1 -> regs
  float4 pa, pb;
  pa = *(const float4*)(gsrc + tid * 4);
  if (tid < 64) pb = *(const float4*)(gsrc + 2048 + tid * 4);
  *(float4*)&buf[0][tid * 4] = pa;
  if (tid < 64) *(float4*)&buf[0][2048 + tid * 4] = pb;
  pa = *(const float4*)(gsrc + PREPSZ + tid * 4);
  if (tid < 64) pb = *(const float4*)(gsrc + PREPSZ + 2048 + tid * 4);
  __syncthreads();

  for (int T = 0; T < 256; T++) {
    const float* bp = buf[T & 1];
    float bt[8], qb[8];
#pragma unroll
    for (int t = 0; t < 8; t++) {
      float4 k1a = *(const float4*)&bp[t * 64 + kp * 8];
      float4 k1b = *(const float4*)&bp[t * 64 + kp * 8 + 4];
      float4 q1a = *(const float4*)&bp[512 + t * 64 + kp * 8];
      float4 q1b = *(const float4*)&bp[512 + t * 64 + kp * 8 + 4];
      bt[t] = k1a.x * S[0] + k1a.y * S[1] + k1a.z * S[2] + k1a.w * S[3] +
              k1b.x * S[4] + k1b.y * S[5] + k1b.z * S[6] + k1b.w * S[7];
      qb[t] = q1a.x * S[0] + q1a.y * S[1] + q1a.z * S[2] + q1a.w * S[3] +
              q1b.x * S[4] + q1b.y * S[5] + q1b.z * S[6] + q1b.w * S[7];
    }
#pragma unroll
    for (int off = 1; off < 8; off <<= 1)
#pragma unroll
      for (int t = 0; t < 8; t++) {
        bt[t] += __shfl_xor(bt[t], off);
        qb[t] += __shfl_xor(qb[t], off);
      }
    float u[8];
#pragma unroll
    for (int t = 0; t < 8; t++) u[t] = bp[1536 + t * 64 + vg * 8 + vv] - bt[t];
#pragma unroll
    for (int t = 0; t < 8; t++) {
      float o = qb[t];
#pragma unroll
      for (int r = 0; r < 8; r++)
        if (r <= t) o += bp[2112 + t * 8 + r] * u[r];
      if (kp == 0)
        y[((size_t)(b * TT) + (size_t)T * 8 + t) * HKk + h * 64 + vg * 8 + vv] = o;
    }
    {
      float4 a7a = *(const float4*)&bp[2048 + kp * 8];
      float4 a7b = *(const float4*)&bp[2048 + kp * 8 + 4];
      S[0] *= a7a.x; S[1] *= a7a.y; S[2] *= a7a.z; S[3] *= a7a.w;
      S[4] *= a7b.x; S[5] *= a7b.y; S[6] *= a7b.z; S[7] *= a7b.w;
#pragma unroll
      for (int r = 0; r < 8; r++) {
        float4 ha = *(const float4*)&bp[1024 + r * 64 + kp * 8];
        float4 hb = *(const float4*)&bp[1024 + r * 64 + kp * 8 + 4];
        float ur = u[r];
        S[0] += ha.x * ur; S[1] += ha.y * ur; S[2] += ha.z * ur; S[3] += ha.w * ur;
        S[4] += hb.x * ur; S[5] += hb.y * ur; S[6] += hb.z * ur; S[7] += hb.w * ur;
      }
    }
    if (T < 255) {
      __syncthreads();
      *(float4*)&buf[(T + 1) & 1][tid * 4] = pa;
      if (tid < 64) *(float4*)&buf[(T + 1) & 1][2048 + tid * 4] = pb;
      if (T + 1 < 255) {
        const float* gn = gsrc + (size_t)(T + 2) * PREPSZ;
        pa = *(const float4*)(gn + tid * 4);
        if (tid < 64) pb = *(const float4*)(gn + 2048 + tid * 4);
      }
      __syncthreads();
    }
  }
}

// ---------- SwiGLU combine in-place on bf16 f ----------
__global__ __launch_bounds__(256) void kmulg(u16* __restrict__ f) {
  size_t i = ((size_t)blockIdx.x * 256 + threadIdx.x) * 8;
  size_t r = i >> 12;
  int c = (int)(i & 4095);
  u16* p = f + r * 8192 + c;
#pragma unroll
  for (int j = 0; j < 8; j++) p[j] = f2bf(bf2f(p[j]) * bf2f(p[j + 4096]));
}

extern "C" void kernel_launch(void* const* d_in, const int* in_sizes, int n_in,
                              void* d_out, int out_size, void* d_ws, size_t ws_size,
                              hipStream_t stream) {
  const float *x = (const float*)d_in[0], *norm_in_w = (const float*)d_in[1],
              *conv_w = (const float*)d_in[2], *conv_b = (const float*)d_in[3],
              *Wq = (const float*)d_in[4], *Wk = (const float*)d_in[5],
              *Wv = (const float*)d_in[6], *Wo = (const float*)d_in[7],
              *Wspike = (const float*)d_in[8], *Wau = (const float*)d_in[9],
              *bau = (const float*)d_in[10], *Wad = (const float*)d_in[11],
              *bad_ = (const float*)d_in[12], *asp = (const float*)d_in[13],
              *Wbeta = (const float*)d_in[14], *bbeta = (const float*)d_in[15],
              *bsp = (const float*)d_in[16], *hnw = (const float*)d_in[17],
              *Wu1 = (const float*)d_in[18], *bu1 = (const float*)d_in[19],
              *Wu2 = (const float*)d_in[20], *bu2 = (const float*)d_in[21],
              *ffw = (const float*)d_in[22], *Wff1 = (const float*)d_in[23],
              *Wff3 = (const float*)d_in[24], *Wff2 = (const float*)d_in[25];
  (void)in_sizes; (void)n_in; (void)out_size; (void)ws_size;

  char* wsb = (char*)d_ws;
  size_t off = 0;
  auto alloc = [&](size_t bytes) {
    void* p = wsb + off;
    off += (bytes + 255) & ~(size_t)255;
    return p;
  };
  float* h    = (float*)alloc((size_t)BTt * DD * 4);       // 16 MiB
  u16*   hc   = (u16*)alloc((size_t)BTt * DD * 2);         // 8
  size_t qoff = off;  // overlay region start (dead before FFN)
  float* X1   = (float*)alloc((size_t)BTt * 2048 * 4);     // 32  q|k|v|drive
  float* ab   = (float*)alloc((size_t)BTt * HKk * 4);      // 8
  float* alph = (float*)alloc((size_t)BTt * HKk * 4);      // 8
  float* bb   = (float*)alloc((size_t)BTt * HH * 4);       // .125
  float* au   = (float*)alloc((size_t)BTt * 64 * 4);       // 1
  float* beta = (float*)alloc((size_t)BTt * HH * 4);       // .125
  float* u1   = (float*)alloc((size_t)BTt * 64 * 4);       // 1
  float* gate = (float*)alloc((size_t)BTt * DD * 4);       // 16
  float* yat  = (float*)alloc((size_t)BTt * HKk * 4);      // 8
  u16* yat_bf = (u16*)alloc((size_t)BTt * HKk * 2);        // 4
  u16* f_bf   = (u16*)(wsb + qoff);  // 64 MiB overlay, dead-region reuse at FFN
  float* y2   = (float*)alloc((size_t)BTt * DD * 4);       // 16
  u16* z_bf   = (u16*)alloc((size_t)BTt * DD * 2);         // 8
  u16* WtX    = (u16*)alloc((size_t)2048 * 1024 * 2);      // 4
  u16* WtO    = (u16*)alloc((size_t)1024 * 512 * 2);       // 1
  u16* WtFF   = (u16*)alloc((size_t)8192 * 1024 * 2);      // 16
  u16* WtF2   = (u16*)alloc((size_t)1024 * 4096 * 2);      // 8
  float* prep = (float*)alloc((size_t)16 * 256 * PREPSZ * 4);  // 36 MiB
  unsigned* masks = (unsigned*)alloc((size_t)16 * 64 * 64 * 4);  // 1 MiB => ~192 MiB total

  // weight transposes (f32 -> bf16, Bt = [N,K] k-contiguous)
  ktrans<<<dim3(16, 32), 256, 0, stream>>>(Wq, WtX + (size_t)0 * 512 * 1024, 1024, 512);
  ktrans<<<dim3(16, 32), 256, 0, stream>>>(Wk, WtX + (size_t)1 * 512 * 1024, 1024, 512);
  ktrans<<<dim3(16, 32), 256, 0, stream>>>(Wv, WtX + (size_t)2 * 512 * 1024, 1024, 512);
  ktrans<<<dim3(16, 32), 256, 0, stream>>>(Wspike, WtX + (size_t)3 * 512 * 1024, 1024, 512);
  ktrans<<<dim3(32, 16), 256, 0, stream>>>(Wo, WtO, 512, 1024);
  ktrans<<<dim3(128, 32), 256, 0, stream>>>(Wff1, WtFF, 1024, 4096);
  ktrans<<<dim3(128, 32), 256, 0, stream>>>(Wff3, WtFF + (size_t)4096 * 1024, 1024, 4096);
  ktrans<<<dim3(32, 128), 256, 0, stream>>>(Wff2, WtF2, 4096, 1024);

  // front end
  krms<<<BTt, 256, 0, stream>>>(x, norm_in_w, h, 0);
  kconv<<<BTt * DD / 256, 256, 0, stream>>>(h, conv_w, conv_b, hc);

  // QKVD projection (MFMA): -> X1 f32 [4096,2048]
  kmfma<0><<<dim3(16, 32), 256, 0, stream>>>(
      hc, 1024, WtX, X1, 2048, BTt, 2048, 1024, nullptr, nullptr, nullptr, 0);

  // small projections (f32 compute)
  kgemm<<<dim3(1, 64), 256, 0, stream>>>(hc, 1, Wau, bau, au, BTt, 64, DD, 1);
  kgemm<<<dim3(8, 64), 256, 0, stream>>>(au, 0, Wad, bad_, ab, BTt, HKk, 64, 0);
  kgemm<<<dim3(1, 64), 256, 0, stream>>>(hc, 1, Wbeta, bbeta, bb, BTt, HH, DD, 0);

  kl2norm<<<BTt * 16 / 4, 256, 0, stream>>>(X1);
  klifA<<<BB * HH, 64, 0, stream>>>(X1 + 1536, 2048, masks);
  klifB<<<BB * HH * 16, 64, 0, stream>>>(masks, ab, bb, asp, bsp, alph, beta);
  kprep<<<16 * 256, 64, 0, stream>>>(X1, alph, beta, prep);
  kscan2<<<16, 512, 0, stream>>>(prep, yat);
  kheadnorm<<<BTt * HH / 4, 256, 0, stream>>>(yat, hnw, yat_bf);

  // gate path (f32)
  kgemm<<<dim3(1, 64), 256, 0, stream>>>(x, 0, Wu1, bu1, u1, BTt, 64, DD, 1);
  kgemm<<<dim3(16, 64), 256, 0, stream>>>(u1, 0, Wu2, bu2, gate, BTt, DD, 64, 2);

  // y2 = x + (yat @ Wo) * gate   (MFMA, f32 out)
  kmfma<2><<<dim3(8, 32), 256, 0, stream>>>(
      yat_bf, 512, WtO, y2, 1024, BTt, 1024, 512, x, gate, nullptr, 0);

  // FFN (MFMA)
  krms<<<BTt, 256, 0, stream>>>(y2, ffw, z_bf, 1);
  kmfma<1><<<dim3(64, 32), 256, 0, stream>>>(
      z_bf, 1024, WtFF, f_bf, 8192, BTt, 8192, 1024, nullptr, nullptr, nullptr, 4096);
  kmulg<<<BTt * 4096 / 8 / 256, 256, 0, stream>>>(f_bf);
  kmfma<3><<<dim3(8, 32), 256, 0, stream>>>(
      f_bf, 8192, WtF2, d_out, 1024, BTt, 1024, 4096, nullptr, nullptr, y2, 0);
}

// Round 12
// 1549.923 us; speedup vs baseline: 1.0914x; 1.0914x over previous
//
#include <hip/hip_runtime.h>
#include <hip/hip_bf16.h>

#define BB 2
#define TT 2048
#define DD 1024
#define HH 8
#define HKk 512
#define BTt 4096   // BB*TT
#define CC 16      // chunk length
#define NT 128     // tiles per bh
#define PREPSZ 4608  // floats per (bh,tile) prep block (18 KiB)
// prep layout: K1 0 | Q1 1024 | KH2 2048 | BV 3072 | A15 4096 | GW 4160 | pad->4608

typedef unsigned short u16;
typedef __attribute__((ext_vector_type(8))) short bf16x8;
typedef __attribute__((ext_vector_type(4))) float f32x4;

__device__ __forceinline__ u16 f2bf(float v) {
  union { float f; unsigned u; } c; c.f = v;
  return (u16)((c.u + 0x7fffu + ((c.u >> 16) & 1u)) >> 16);  // RNE
}
__device__ __forceinline__ float bf2f(u16 v) {
  union { unsigned u; float f; } c; c.u = ((unsigned)v) << 16; return c.f;
}
__device__ __forceinline__ float sigm(float x) { return 1.f / (1.f + expf(-x)); }

// ---------- weight transpose + cast: dst_bf16[n*K+k] = src_f32[k*N+n] ----------
__global__ __launch_bounds__(256) void ktrans(const float* __restrict__ src,
                                              u16* __restrict__ dst, int K, int N) {
  __shared__ u16 t[32][33];
  int n0 = blockIdx.x * 32, k0 = blockIdx.y * 32;
  int tx = threadIdx.x & 31, ty0 = threadIdx.x >> 5;
#pragma unroll
  for (int i = 0; i < 32; i += 8)
    t[ty0 + i][tx] = f2bf(src[(size_t)(k0 + ty0 + i) * N + n0 + tx]);
  __syncthreads();
#pragma unroll
  for (int i = 0; i < 32; i += 8)
    dst[(size_t)(n0 + ty0 + i) * K + k0 + tx] = t[tx][ty0 + i];
}

// ---------- RMS norm over 1024 cols ----------
__global__ __launch_bounds__(256) void krms(const float* __restrict__ x,
                                            const float* __restrict__ w,
                                            void* __restrict__ out, int obf) {
  size_t row = blockIdx.x;
  __shared__ float red[4];
  float vals[4];
  float s = 0.f;
#pragma unroll
  for (int i = 0; i < 4; i++) {
    vals[i] = x[row * DD + threadIdx.x + i * 256];
    s += vals[i] * vals[i];
  }
#pragma unroll
  for (int off = 32; off; off >>= 1) s += __shfl_xor(s, off);
  if ((threadIdx.x & 63) == 0) red[threadIdx.x >> 6] = s;
  __syncthreads();
  float tot = red[0] + red[1] + red[2] + red[3];
  float sc = rsqrtf(tot * (1.f / DD) + 1e-6f);
#pragma unroll
  for (int i = 0; i < 4; i++) {
    size_t idx = row * DD + threadIdx.x + i * 256;
    float vv = vals[i] * sc * w[threadIdx.x + i * 256];
    if (obf) ((u16*)out)[idx] = f2bf(vv);
    else ((float*)out)[idx] = vv;
  }
}

// ---------- causal depthwise conv (KW=4) + bias + SiLU: f32 -> bf16 ----------
__global__ __launch_bounds__(256) void kconv(const float* __restrict__ hin,
                                             const float* __restrict__ cw,
                                             const float* __restrict__ cb,
                                             u16* __restrict__ hout) {
  size_t i = (size_t)blockIdx.x * 256 + threadIdx.x;
  int d = (int)(i & 1023);
  int bt = (int)(i >> 10);
  int b = bt >> 11, t = bt & 2047;
  float acc = cb[d];
#pragma unroll
  for (int j = 0; j < 4; j++) {
    int tt = t - 3 + j;
    if (tt >= 0) acc += hin[(((size_t)(b * TT + tt)) << 10) + d] * cw[d * 4 + j];
  }
  hout[i] = f2bf(acc * sigm(acc));
}

// ---------- small f32-compute GEMM ----------
__global__ __launch_bounds__(256) void kgemm(const void* __restrict__ A, int abf,
                                             const float* __restrict__ Bm,
                                             const float* __restrict__ bias,
                                             float* __restrict__ C,
                                             int M, int N, int K, int act) {
  __shared__ __align__(16) float As[16][64];
  __shared__ __align__(16) float Bs[16][64];
  int tid = threadIdx.x;
  int tx = tid & 15, ty = tid >> 4;
  int row0 = blockIdx.y * 64, col0 = blockIdx.x * 64;
  float acc[4][4] = {};
  for (int k0 = 0; k0 < K; k0 += 16) {
#pragma unroll
    for (int l = 0; l < 4; l++) {
      int e = tid * 4 + l;
      int m = e >> 4, kk = e & 15;
      int gr = row0 + m;
      size_t ai = (size_t)gr * K + k0 + kk;
      As[kk][m] = (gr < M) ? (abf ? bf2f(((const u16*)A)[ai]) : ((const float*)A)[ai]) : 0.f;
    }
#pragma unroll
    for (int l = 0; l < 4; l++) {
      int e = tid + l * 256;
      int kk = e >> 6, n = e & 63;
      int gc = col0 + n;
      Bs[kk][n] = (gc < N) ? Bm[(size_t)(k0 + kk) * N + gc] : 0.f;
    }
    __syncthreads();
#pragma unroll
    for (int kk = 0; kk < 16; kk++) {
      float4 av = *(const float4*)&As[kk][ty * 4];
      float4 bv = *(const float4*)&Bs[kk][tx * 4];
      float a[4] = {av.x, av.y, av.z, av.w};
      float b[4] = {bv.x, bv.y, bv.z, bv.w};
#pragma unroll
      for (int i = 0; i < 4; i++)
#pragma unroll
        for (int j = 0; j < 4; j++) acc[i][j] += a[i] * b[j];
    }
    __syncthreads();
  }
#pragma unroll
  for (int i = 0; i < 4; i++) {
    int r = row0 + ty * 4 + i;
    if (r >= M) continue;
#pragma unroll
    for (int j = 0; j < 4; j++) {
      int cc = col0 + tx * 4 + j;
      if (cc >= N) continue;
      float vv = acc[i][j];
      if (bias) vv += bias[cc];
      if (act == 1) vv = vv * sigm(vv);
      else if (act == 2) vv = sigm(vv);
      C[(size_t)r * N + cc] = vv;
    }
  }
}

// ---------- big MFMA GEMM ----------
template <int EPI>
__global__ __launch_bounds__(256) void kmfma(
    const u16* __restrict__ A, int lda, const u16* __restrict__ Bt,
    void* __restrict__ C, int ldc, int M, int N, int K,
    const float* __restrict__ g1f, const float* __restrict__ g2f,
    const float* __restrict__ f1, int silucut) {
  __shared__ __align__(16) u16 As[128 * 72];
  __shared__ __align__(16) u16 Bs[128 * 72];
  int tid = threadIdx.x;
  int lane = tid & 63, wv = tid >> 6;
  int m0 = (wv & 1) * 64, n0 = (wv >> 1) * 64;
  int ml = lane & 15, kq = (lane >> 4) << 3;
  int row0 = blockIdx.y * 128, col0 = blockIdx.x * 128;
  int sr = tid >> 3, sc = (tid & 7) * 8;

  f32x4 acc[4][4];
#pragma unroll
  for (int i = 0; i < 4; i++)
#pragma unroll
    for (int j = 0; j < 4; j++) acc[i][j] = (f32x4){0.f, 0.f, 0.f, 0.f};

  for (int k0 = 0; k0 < K; k0 += 64) {
    __syncthreads();
#pragma unroll
    for (int ri = 0; ri < 4; ri++) {
      bf16x8 a_ld = *(const bf16x8*)&A[(size_t)(row0 + sr + ri * 32) * lda + k0 + sc];
      bf16x8 b_ld = *(const bf16x8*)&Bt[(size_t)(col0 + sr + ri * 32) * K + k0 + sc];
      *(bf16x8*)&As[(sr + ri * 32) * 72 + sc] = a_ld;
      *(bf16x8*)&Bs[(sr + ri * 32) * 72 + sc] = b_ld;
    }
    __syncthreads();
#pragma unroll
    for (int kk = 0; kk < 64; kk += 32) {
      bf16x8 af[4], bfr[4];
#pragma unroll
      for (int i = 0; i < 4; i++)
        af[i] = *(const bf16x8*)&As[(m0 + i * 16 + ml) * 72 + kk + kq];
#pragma unroll
      for (int j = 0; j < 4; j++)
        bfr[j] = *(const bf16x8*)&Bs[(n0 + j * 16 + ml) * 72 + kk + kq];
#pragma unroll
      for (int i = 0; i < 4; i++)
#pragma unroll
        for (int j = 0; j < 4; j++)
          acc[i][j] = __builtin_amdgcn_mfma_f32_16x16x32_bf16(af[i], bfr[j], acc[i][j], 0, 0, 0);
    }
  }
  int rbase = row0 + m0 + ((lane >> 4) << 2);
#pragma unroll
  for (int i = 0; i < 4; i++) {
#pragma unroll
    for (int j = 0; j < 4; j++) {
      int gc = col0 + n0 + j * 16 + ml;
#pragma unroll
      for (int r = 0; r < 4; r++) {
        int gr = rbase + i * 16 + r;
        float v = acc[i][j][r];
        size_t idx = (size_t)gr * ldc + gc;
        if (EPI == 0) {
          ((float*)C)[idx] = v;
        } else if (EPI == 1) {
          if (gc < silucut) v = v * sigm(v);
          ((u16*)C)[idx] = f2bf(v);
        } else if (EPI == 2) {
          ((float*)C)[idx] = g1f[idx] + v * g2f[idx];
        } else {
          ((float*)C)[idx] = f1[idx] + v;
        }
      }
    }
  }
}

// ---------- L2 normalize 64-wide slices of X1 (q|k halves) ----------
__global__ __launch_bounds__(256) void kl2norm(float* __restrict__ X1) {
  int lane = threadIdx.x & 63;
  size_t r64 = (size_t)blockIdx.x * 4 + (threadIdx.x >> 6);
  size_t t = r64 >> 4;
  int sl = (int)(r64 & 15);
  size_t idx = t * 2048 + sl * 64 + lane;
  float vv = X1[idx];
  float s = vv * vv;
#pragma unroll
  for (int off = 32; off; off >>= 1) s += __shfl_xor(s, off);
  X1[idx] = vv / (sqrtf(s) + 1e-6f);
}

// ---------- headwise RMS norm: yat f32 -> bf16 ----------
__global__ __launch_bounds__(256) void kheadnorm(const float* __restrict__ y,
                                                 const float* __restrict__ hw,
                                                 u16* __restrict__ yo) {
  int lane = threadIdx.x & 63;
  size_t r = (size_t)blockIdx.x * 4 + (threadIdx.x >> 6);
  int h = (int)(r & 7);
  float vv = y[r * 64 + lane];
  float s = vv * vv;
#pragma unroll
  for (int off = 32; off; off >>= 1) s += __shfl_xor(s, off);
  yo[r * 64 + lane] = f2bf(vv * rsqrtf(s * (1.f / 64.f) + 1e-6f) * hw[h * 64 + lane]);
}

// ---------- klifA: membrane recurrence only -> packed spike bitmasks ----------
__global__ __launch_bounds__(64) void klifA(const float* __restrict__ dr, int drs,
                                            unsigned* __restrict__ masks) {
  int bh = blockIdx.x;
  int b = bh >> 3, h = bh & 7;
  int lane = threadIdx.x;
  float cur[32], nxt[32];
#pragma unroll
  for (int i = 0; i < 32; i++)
    cur[i] = dr[(size_t)(b * TT + i) * drs + h * 64 + lane];
  float mem = 0.f;
  for (int t0 = 0; t0 < TT; t0 += 32) {
    if (t0 + 32 < TT) {
#pragma unroll
      for (int i = 0; i < 32; i++)
        nxt[i] = dr[(size_t)(b * TT + t0 + 32 + i) * drs + h * 64 + lane];
    }
    unsigned m = 0;
#pragma unroll
    for (int i = 0; i < 32; i++) {
      mem = 0.9f * mem + cur[i];
      int s = (mem > 0.5f) ? 1 : 0;
      mem -= s ? 0.5f : 0.f;
      m |= ((unsigned)s) << i;
    }
    masks[((size_t)bh * 64 + (t0 >> 5)) * 64 + lane] = m;
#pragma unroll
    for (int i = 0; i < 32; i++) cur[i] = nxt[i];
  }
}

// ---------- klifB: gates from spike masks, fully parallel ----------
__global__ __launch_bounds__(64) void klifB(const unsigned* __restrict__ masks,
                                            const float* __restrict__ ab,
                                            const float* __restrict__ bb,
                                            const float* __restrict__ asp,
                                            const float* __restrict__ bsp,
                                            float* __restrict__ alpha,
                                            float* __restrict__ beta) {
  int blk = blockIdx.x;
  int bh = blk >> 4, tc = blk & 15;
  int b = bh >> 3, h = bh & 7;
  int lane = threadIdx.x;
  float aspk = asp[h * 64 + lane];
  float bspk = bsp[h * 64 + lane];
#pragma unroll
  for (int g = 0; g < 2; g++) {
    size_t row0 = (size_t)(b * TT) + tc * 128 + g * 64;
    unsigned m0 = masks[((size_t)bh * 64 + (tc * 4 + g * 2 + 0)) * 64 + lane];
    unsigned m1 = masks[((size_t)bh * 64 + (tc * 4 + g * 2 + 1)) * 64 + lane];
    float bbv = bb[(row0 + lane) * HH + h];
#pragma unroll
    for (int tt = 0; tt < 64; tt++) {
      unsigned mw = (tt < 32) ? m0 : m1;
      int s = (mw >> (tt & 31)) & 1;
      unsigned long long act = __ballot(s != 0);
      float sp = (float)s;
      float r2 = sp * bspk;
#pragma unroll
      for (int off = 32; off; off >>= 1) r2 += __shfl_xor(r2, off);
      float bbi = __shfl(bbv, tt);  // all lanes EXEC-active (r8 lesson)
      size_t rt = row0 + tt;
      float abv = ab[rt * HKk + h * 64 + lane];
      int active = (act != 0ull);
      alpha[rt * HKk + h * 64 + lane] = active ? sigm(abv + aspk * sp) : 1.f;
      if (lane == 0) beta[rt * HH + h] = active ? sigm(bbi + r2) : 0.f;
    }
  }
}

// ---------- kprep: chunk C=16 UT-transform precompute ----------
__global__ __launch_bounds__(64) void kprep(const float* __restrict__ X1,
                                            const float* __restrict__ alph,
                                            const float* __restrict__ beta,
                                            float* __restrict__ prep) {
  int blk = blockIdx.x;          // 16 bh * 128 tiles
  int bh = blk >> 7, T = blk & 127;
  int b = bh >> 3, h = bh & 7;
  int lane = threadIdx.x;
  size_t row0 = (size_t)(b * TT) + (size_t)T * CC;
  float* out = prep + (size_t)blk * PREPSZ;
  __shared__ float sKP[CC][64], sKiP[CC][64], sQP[CC][64];
  __shared__ float sBC[CC * CC], sG[CC * CC], sW[CC * CC], sBeta[CC];

  float Pt[CC], kv[CC], kh[CC];
  {
    float P = 1.f;
#pragma unroll
    for (int t = 0; t < CC; t++) {
      size_t rt = row0 + t;
      float a = alph[rt * HKk + h * 64 + lane];
      kv[t] = X1[rt * 2048 + h * 64 + 512 + lane];
      float qv = X1[rt * 2048 + h * 64 + lane];
      P *= a;
      Pt[t] = P;
      float qp = qv * P;
      sQP[t][lane] = qp;
      out[1024 + t * 64 + lane] = qp;  // Q1
    }
    float PC = Pt[CC - 1];
#pragma unroll
    for (int t = 0; t < CC; t++) {
      float KiPv = kv[t] / Pt[t];
      sKP[t][lane] = kv[t] * Pt[t];
      sKiP[t][lane] = KiPv;
      kh[t] = PC * KiPv;
    }
    out[4096 + lane] = PC;  // A15
  }
  if (lane < CC) sBeta[lane] = beta[(row0 + lane) * HH + h];
  __syncthreads();
#pragma unroll
  for (int t = 0; t < CC; t++) out[t * 64 + lane] = sBeta[t] * kv[t] * Pt[t];  // K1

  // phase 2: 256 (t,s) pairs, 4 per lane
#pragma unroll
  for (int i = 0; i < 4; i++) {
    int p = lane + 64 * i;
    int t2 = p >> 4, s2 = p & 15;
    float ac = 0.f, ag = 0.f;
#pragma unroll
    for (int k = 0; k < 64; k++) {
      float kip = sKiP[s2][k];
      ac += sKP[t2][k] * kip;
      ag += sQP[t2][k] * kip;
    }
    sBC[p] = (t2 > s2) ? sBeta[t2] * ac : 0.f;
    sG[p] = (t2 >= s2) ? ag : 0.f;
    sW[p] = 0.f;
  }
  __syncthreads();
  if (lane < CC) sW[lane * CC + lane] = 1.f;
  __syncthreads();

  // phase 3a: W = (I + strictlower(BC))^{-1}, forward substitution
  for (int t = 1; t < CC; t++) {
    if (lane < t) {
      float a = -sBC[t * CC + lane];
      for (int s = lane + 1; s < t; s++) a -= sBC[t * CC + s] * sW[s * CC + lane];
      sW[t * CC + lane] = a;
    }
    __syncthreads();
  }
  // phase 3b: GW = G * W (lower incl diag), 4 entries per lane
#pragma unroll
  for (int i = 0; i < 4; i++) {
    int p = lane + 64 * i;
    int t2 = p >> 4, s2 = p & 15;
    float gw = 0.f;
    if (s2 <= t2)
      for (int m = s2; m <= t2; m++) gw += sG[t2 * CC + m] * sW[m * CC + s2];
    out[4160 + p] = gw;
  }
  // phase 4: KH2_r = sum_{s>=r} kh_s * W[s][r]   (lane = k)
#pragma unroll
  for (int r = 0; r < CC; r++) {
    float acc = 0.f;
    for (int s = r; s < CC; s++) acc += kh[s] * sW[s * CC + r];
    out[2048 + r * 64 + lane] = acc;
  }
  // phase 5: BV_t = beta_t * v_t
#pragma unroll
  for (int t = 0; t < CC; t++)
    out[3072 + t * 64 + lane] = sBeta[t] * X1[(row0 + t) * 2048 + h * 64 + 1024 + lane];
}

// ---------- kscan2: sequential chunk walker, C=16, r10 structure ----------
// 128 independent single-wave blocks = bh(16) x vg(8); no inter-wave coupling
// (r11's 8-wave sharing regressed: latency-bound, not BW-bound). Half the
// serial tiles of C=8.
__global__ __launch_bounds__(64) void kscan2(const float* __restrict__ prep,
                                             float* __restrict__ y) {
  int bid = blockIdx.x;
  int bh = bid >> 3, vg = bid & 7;
  int b = bh >> 3, h = bh & 7;
  int lane = threadIdx.x;
  int kp = lane & 7, vv = lane >> 3;
  const float* gsrc = prep + (size_t)bh * NT * PREPSZ;
  __shared__ __align__(16) float buf[2][PREPSZ];
  float S[8];
#pragma unroll
  for (int j = 0; j < 8; j++) S[j] = 0.f;

  float4 pf[18];
  const float* g0 = gsrc + (size_t)lane * 72;
#pragma unroll
  for (int i = 0; i < 18; i++) pf[i] = *(const float4*)(g0 + i * 4);
#pragma unroll
  for (int i = 0; i < 18; i++) *(float4*)&buf[0][lane * 72 + i * 4] = pf[i];
#pragma unroll
  for (int i = 0; i < 18; i++) pf[i] = *(const float4*)(g0 + PREPSZ + i * 4);
  __syncthreads();

  for (int T = 0; T < NT; T++) {
    const float* bp = buf[T & 1];
    float bt[CC], qb[CC];
#pragma unroll
    for (int t = 0; t < CC; t++) {
      float4 k1a = *(const float4*)&bp[t * 64 + kp * 8];
      float4 k1b = *(const float4*)&bp[t * 64 + kp * 8 + 4];
      float4 q1a = *(const float4*)&bp[1024 + t * 64 + kp * 8];
      float4 q1b = *(const float4*)&bp[1024 + t * 64 + kp * 8 + 4];
      bt[t] = k1a.x * S[0] + k1a.y * S[1] + k1a.z * S[2] + k1a.w * S[3] +
              k1b.x * S[4] + k1b.y * S[5] + k1b.z * S[6] + k1b.w * S[7];
      qb[t] = q1a.x * S[0] + q1a.y * S[1] + q1a.z * S[2] + q1a.w * S[3] +
              q1b.x * S[4] + q1b.y * S[5] + q1b.z * S[6] + q1b.w * S[7];
    }
#pragma unroll
    for (int off = 1; off < 8; off <<= 1)
#pragma unroll
      for (int t = 0; t < CC; t++) {
        bt[t] += __shfl_xor(bt[t], off);
        qb[t] += __shfl_xor(qb[t], off);
      }
    float u[CC];
#pragma unroll
    for (int t = 0; t < CC; t++) u[t] = bp[3072 + t * 64 + vg * 8 + vv] - bt[t];
#pragma unroll
    for (int t = 0; t < CC; t++) {
      float o = qb[t];
#pragma unroll
      for (int r = 0; r < CC; r++)
        if (r <= t) o += bp[4160 + t * CC + r] * u[r];
      if (kp == 0)
        y[((size_t)(b * TT) + (size_t)T * CC + t) * HKk + h * 64 + vg * 8 + vv] = o;
    }
    {
      float4 a7a = *(const float4*)&bp[4096 + kp * 8];
      float4 a7b = *(const float4*)&bp[4096 + kp * 8 + 4];
      S[0] *= a7a.x; S[1] *= a7a.y; S[2] *= a7a.z; S[3] *= a7a.w;
      S[4] *= a7b.x; S[5] *= a7b.y; S[6] *= a7b.z; S[7] *= a7b.w;
#pragma unroll
      for (int r = 0; r < CC; r++) {
        float4 ha = *(const float4*)&bp[2048 + r * 64 + kp * 8];
        float4 hb = *(const float4*)&bp[2048 + r * 64 + kp * 8 + 4];
        float ur = u[r];
        S[0] += ha.x * ur; S[1] += ha.y * ur; S[2] += ha.z * ur; S[3] += ha.w * ur;
        S[4] += hb.x * ur; S[5] += hb.y * ur; S[6] += hb.z * ur; S[7] += hb.w * ur;
      }
    }
    if (T < NT - 1) {
      __syncthreads();
#pragma unroll
      for (int i = 0; i < 18; i++) *(float4*)&buf[(T + 1) & 1][lane * 72 + i * 4] = pf[i];
      if (T + 1 < NT - 1) {
        const float* gn = g0 + (size_t)(T + 2) * PREPSZ;
#pragma unroll
        for (int i = 0; i < 18; i++) pf[i] = *(const float4*)(gn + i * 4);
      }
      __syncthreads();
    }
  }
}

// ---------- SwiGLU combine in-place on bf16 f ----------
__global__ __launch_bounds__(256) void kmulg(u16* __restrict__ f) {
  size_t i = ((size_t)blockIdx.x * 256 + threadIdx.x) * 8;
  size_t r = i >> 12;
  int c = (int)(i & 4095);
  u16* p = f + r * 8192 + c;
#pragma unroll
  for (int j = 0; j < 8; j++) p[j] = f2bf(bf2f(p[j]) * bf2f(p[j + 4096]));
}

extern "C" void kernel_launch(void* const* d_in, const int* in_sizes, int n_in,
                              void* d_out, int out_size, void* d_ws, size_t ws_size,
                              hipStream_t stream) {
  const float *x = (const float*)d_in[0], *norm_in_w = (const float*)d_in[1],
              *conv_w = (const float*)d_in[2], *conv_b = (const float*)d_in[3],
              *Wq = (const float*)d_in[4], *Wk = (const float*)d_in[5],
              *Wv = (const float*)d_in[6], *Wo = (const float*)d_in[7],
              *Wspike = (const float*)d_in[8], *Wau = (const float*)d_in[9],
              *bau = (const float*)d_in[10], *Wad = (const float*)d_in[11],
              *bad_ = (const float*)d_in[12], *asp = (const float*)d_in[13],
              *Wbeta = (const float*)d_in[14], *bbeta = (const float*)d_in[15],
              *bsp = (const float*)d_in[16], *hnw = (const float*)d_in[17],
              *Wu1 = (const float*)d_in[18], *bu1 = (const float*)d_in[19],
              *Wu2 = (const float*)d_in[20], *bu2 = (const float*)d_in[21],
              *ffw = (const float*)d_in[22], *Wff1 = (const float*)d_in[23],
              *Wff3 = (const float*)d_in[24], *Wff2 = (const float*)d_in[25];
  (void)in_sizes; (void)n_in; (void)out_size; (void)ws_size;

  char* wsb = (char*)d_ws;
  size_t off = 0;
  auto alloc = [&](size_t bytes) {
    void* p = wsb + off;
    off += (bytes + 255) & ~(size_t)255;
    return p;
  };
  float* h    = (float*)alloc((size_t)BTt * DD * 4);       // 16 MiB
  u16*   hc   = (u16*)alloc((size_t)BTt * DD * 2);         // 8
  size_t qoff = off;  // overlay region start (dead before FFN)
  float* X1   = (float*)alloc((size_t)BTt * 2048 * 4);     // 32  q|k|v|drive
  float* ab   = (float*)alloc((size_t)BTt * HKk * 4);      // 8
  float* alph = (float*)alloc((size_t)BTt * HKk * 4);      // 8
  float* bb   = (float*)alloc((size_t)BTt * HH * 4);       // .125
  float* au   = (float*)alloc((size_t)BTt * 64 * 4);       // 1
  float* beta = (float*)alloc((size_t)BTt * HH * 4);       // .125
  float* u1   = (float*)alloc((size_t)BTt * 64 * 4);       // 1
  float* gate = (float*)alloc((size_t)BTt * DD * 4);       // 16
  float* yat  = (float*)alloc((size_t)BTt * HKk * 4);      // 8
  u16* yat_bf = (u16*)alloc((size_t)BTt * HKk * 2);        // 4
  u16* f_bf   = (u16*)(wsb + qoff);  // 64 MiB overlay, dead-region reuse at FFN
  float* y2   = (float*)alloc((size_t)BTt * DD * 4);       // 16
  u16* z_bf   = (u16*)alloc((size_t)BTt * DD * 2);         // 8
  u16* WtX    = (u16*)alloc((size_t)2048 * 1024 * 2);      // 4
  u16* WtO    = (u16*)alloc((size_t)1024 * 512 * 2);       // 1
  u16* WtFF   = (u16*)alloc((size_t)8192 * 1024 * 2);      // 16
  u16* WtF2   = (u16*)alloc((size_t)1024 * 4096 * 2);      // 8
  float* prep = (float*)alloc((size_t)16 * NT * PREPSZ * 4);   // 36 MiB
  unsigned* masks = (unsigned*)alloc((size_t)16 * 64 * 64 * 4);  // 1 MiB

  // weight transposes (f32 -> bf16, Bt = [N,K] k-contiguous)
  ktrans<<<dim3(16, 32), 256, 0, stream>>>(Wq, WtX + (size_t)0 * 512 * 1024, 1024, 512);
  ktrans<<<dim3(16, 32), 256, 0, stream>>>(Wk, WtX + (size_t)1 * 512 * 1024, 1024, 512);
  ktrans<<<dim3(16, 32), 256, 0, stream>>>(Wv, WtX + (size_t)2 * 512 * 1024, 1024, 512);
  ktrans<<<dim3(16, 32), 256, 0, stream>>>(Wspike, WtX + (size_t)3 * 512 * 1024, 1024, 512);
  ktrans<<<dim3(32, 16), 256, 0, stream>>>(Wo, WtO, 512, 1024);
  ktrans<<<dim3(128, 32), 256, 0, stream>>>(Wff1, WtFF, 1024, 4096);
  ktrans<<<dim3(128, 32), 256, 0, stream>>>(Wff3, WtFF + (size_t)4096 * 1024, 1024, 4096);
  ktrans<<<dim3(32, 128), 256, 0, stream>>>(Wff2, WtF2, 4096, 1024);

  // front end
  krms<<<BTt, 256, 0, stream>>>(x, norm_in_w, h, 0);
  kconv<<<BTt * DD / 256, 256, 0, stream>>>(h, conv_w, conv_b, hc);

  // QKVD projection (MFMA): -> X1 f32 [4096,2048]
  kmfma<0><<<dim3(16, 32), 256, 0, stream>>>(
      hc, 1024, WtX, X1, 2048, BTt, 2048, 1024, nullptr, nullptr, nullptr, 0);

  // small projections (f32 compute)
  kgemm<<<dim3(1, 64), 256, 0, stream>>>(hc, 1, Wau, bau, au, BTt, 64, DD, 1);
  kgemm<<<dim3(8, 64), 256, 0, stream>>>(au, 0, Wad, bad_, ab, BTt, HKk, 64, 0);
  kgemm<<<dim3(1, 64), 256, 0, stream>>>(hc, 1, Wbeta, bbeta, bb, BTt, HH, DD, 0);

  kl2norm<<<BTt * 16 / 4, 256, 0, stream>>>(X1);
  klifA<<<BB * HH, 64, 0, stream>>>(X1 + 1536, 2048, masks);
  klifB<<<BB * HH * 16, 64, 0, stream>>>(masks, ab, bb, asp, bsp, alph, beta);
  kprep<<<16 * NT, 64, 0, stream>>>(X1, alph, beta, prep);
  kscan2<<<16 * 8, 64, 0, stream>>>(prep, yat);
  kheadnorm<<<BTt * HH / 4, 256, 0, stream>>>(yat, hnw, yat_bf);

  // gate path (f32)
  kgemm<<<dim3(1, 64), 256, 0, stream>>>(x, 0, Wu1, bu1, u1, BTt, 64, DD, 1);
  kgemm<<<dim3(16, 64), 256, 0, stream>>>(u1, 0, Wu2, bu2, gate, BTt, DD, 64, 2);

  // y2 = x + (yat @ Wo) * gate   (MFMA, f32 out)
  kmfma<2><<<dim3(8, 32), 256, 0, stream>>>(
      yat_bf, 512, WtO, y2, 1024, BTt, 1024, 512, x, gate, nullptr, 0);

  // FFN (MFMA)
  krms<<<BTt, 256, 0, stream>>>(y2, ffw, z_bf, 1);
  kmfma<1><<<dim3(64, 32), 256, 0, stream>>>(
      z_bf, 1024, WtFF, f_bf, 8192, BTt, 8192, 1024, nullptr, nullptr, nullptr, 4096);
  kmulg<<<BTt * 4096 / 8 / 256, 256, 0, stream>>>(f_bf);
  kmfma<3><<<dim3(8, 32), 256, 0, stream>>>(
      f_bf, 8192, WtF2, d_out, 1024, BTt, 1024, 4096, nullptr, nullptr, y2, 0);
}